// Round 5
// baseline (347.407 us; speedup 1.0000x reference)
//
#include <hip/hip_runtime.h>
#include <hip/hip_bf16.h>

typedef __bf16 bf16x8 __attribute__((ext_vector_type(8)));
typedef __bf16 bf16x4 __attribute__((ext_vector_type(4)));
typedef float floatx4 __attribute__((ext_vector_type(4)));

#define MFMA16(a, b, c) __builtin_amdgcn_mfma_f32_16x16x32_bf16(a, b, c, 0, 0, 0)
#define AS1 __attribute__((address_space(1)))
#define AS3 __attribute__((address_space(3)))

constexpr int D = 1024;
constexpr int L = 2048;
constexpr int BB = 2;
constexpr int DH = 64;
constexpr float NEG_BIG = -1e30f;                 // finite -inf stand-in (fast-math safe)
constexpr float SCALE_LOG2E = 0.125f * 1.4426950408889634f;  // folded into Q projection

// async global->LDS, 16B per lane (dest = wave-uniform base + lane*16)
__device__ __forceinline__ void gld16(const __bf16* g, __bf16* l) {
  __builtin_amdgcn_global_load_lds((AS1 void*)g, (AS3 void*)l, 16, 0, 0);
}

// ---------------------------------------------------------------------------
// Convert fp32 x (q,k,v inputs) -> canonical bf16 [3][4096][1024]
// ---------------------------------------------------------------------------
__global__ __launch_bounds__(256) void cvt_x(const float* __restrict__ xq, const float* __restrict__ xk,
                                             const float* __restrict__ xv, __bf16* __restrict__ out) {
  const int z = blockIdx.z;
  const float* src = z == 0 ? xq : z == 1 ? xk : xv;
  __bf16* dst = out + (size_t)z * BB * L * D;
  const int N = BB * L * D;
  const int stride = gridDim.x * 256 * 4;
  for (int i = (blockIdx.x * 256 + threadIdx.x) * 4; i < N; i += stride) {
    float4 f = *(const float4*)&src[i];
    bf16x4 b = {(__bf16)f.x, (__bf16)f.y, (__bf16)f.z, (__bf16)f.w};
    *(bf16x4*)&dst[i] = b;
  }
}

// ---------------------------------------------------------------------------
// Transpose 4 fp32 weight matrices W[K][N] -> canonical bf16 Wt[N][K]
// ---------------------------------------------------------------------------
__global__ void transpose_w(const float* __restrict__ w0, const float* __restrict__ w1,
                            const float* __restrict__ w2, const float* __restrict__ w3,
                            __bf16* __restrict__ out) {
  __shared__ __bf16 tile[32][33];
  int mat = blockIdx.z;
  const float* src = mat == 0 ? w0 : mat == 1 ? w1 : mat == 2 ? w2 : w3;
  __bf16* dst = out + (size_t)mat * D * D;
  int bx = blockIdx.x * 32, by = blockIdx.y * 32;
  int tx = threadIdx.x, ty = threadIdx.y;  // block (32, 8)
#pragma unroll
  for (int i = 0; i < 32; i += 8)
    tile[ty + i][tx] = (__bf16)src[(size_t)(by + ty + i) * D + bx + tx];
  __syncthreads();
#pragma unroll
  for (int i = 0; i < 32; i += 8)
    dst[(size_t)(bx + ty + i) * D + by + tx] = tile[tx][ty + i];
}

// ---------------------------------------------------------------------------
// m97-style GEMM main loop: 128x128 tile, BK=32, global_load_lds width-16,
// unpadded LDS [row][32] (layout must match lane order - no padding allowed).
// ---------------------------------------------------------------------------
__device__ __forceinline__ void gemm_core(const __bf16* __restrict__ A, const __bf16* __restrict__ Bt,
                                          __bf16* sA, __bf16* sB, int m0, int n0,
                                          int wm, int wn, int l15, int quad, int t,
                                          floatx4 (&acc)[4][4]) {
  const int lr = t >> 2;           // 0..63
  const int lc = (t & 3) * 8;      // 0,8,16,24
  for (int kb = 0; kb < 1024; kb += 32) {
    gld16(&A[(size_t)(m0 + lr) * 1024 + kb + lc],       &sA[lr * 32 + lc]);
    gld16(&A[(size_t)(m0 + 64 + lr) * 1024 + kb + lc],  &sA[(64 + lr) * 32 + lc]);
    gld16(&Bt[(size_t)(n0 + lr) * 1024 + kb + lc],      &sB[lr * 32 + lc]);
    gld16(&Bt[(size_t)(n0 + 64 + lr) * 1024 + kb + lc], &sB[(64 + lr) * 32 + lc]);
    __syncthreads();

    bf16x8 af[4], bf_[4];
#pragma unroll
    for (int i = 0; i < 4; i++)
      af[i] = *(const bf16x8*)&sA[(wm * 64 + i * 16 + l15) * 32 + quad * 8];
#pragma unroll
    for (int j = 0; j < 4; j++)
      bf_[j] = *(const bf16x8*)&sB[(wn * 64 + j * 16 + l15) * 32 + quad * 8];
#pragma unroll
    for (int i = 0; i < 4; i++)
#pragma unroll
      for (int j = 0; j < 4; j++)
        acc[i][j] = MFMA16(af[i], bf_[j], acc[i][j]);
    __syncthreads();
  }
}

// ---------------------------------------------------------------------------
// QKV projection. z=0: Q scaled by 0.125*log2e, scatter [bh][l][dh].
// z=1: K scatter [bh][l][dh].  z=2: V scatter TRANSPOSED [bh][dh][L].
// ---------------------------------------------------------------------------
__global__ __launch_bounds__(256) void gemm_proj(const __bf16* __restrict__ xc, const __bf16* __restrict__ wt,
                                                 const float* __restrict__ bq, const float* __restrict__ bk,
                                                 const float* __restrict__ bv, __bf16* __restrict__ qkv) {
  __shared__ __align__(16) __bf16 sA[128 * 32];
  __shared__ __align__(16) __bf16 sB[128 * 32];
  const int z = blockIdx.z;
  const __bf16* A = xc + (size_t)z * BB * L * D;
  const __bf16* Bt = wt + (size_t)z * D * D;
  const float* bias = z == 0 ? bq : z == 1 ? bk : bv;
  __bf16* dst = qkv + (size_t)z * BB * L * D;

  const int t = threadIdx.x;
  const int lane = t & 63;
  const int w = t >> 6;
  const int wm = w >> 1, wn = w & 1;
  const int l15 = lane & 15, quad = lane >> 4;
  const int m0 = blockIdx.y * 128, n0 = blockIdx.x * 128;

  floatx4 acc[4][4];
#pragma unroll
  for (int i = 0; i < 4; i++)
#pragma unroll
    for (int j = 0; j < 4; j++) acc[i][j] = (floatx4){0.f, 0.f, 0.f, 0.f};

  gemm_core(A, Bt, sA, sB, m0, n0, wm, wn, l15, quad, t, acc);

  float bvv[4];
#pragma unroll
  for (int j = 0; j < 4; j++) bvv[j] = bias[n0 + wn * 64 + j * 16 + l15];

#pragma unroll
  for (int i = 0; i < 4; i++) {
    const int rowb = m0 + wm * 64 + i * 16 + quad * 4;
#pragma unroll
    for (int j = 0; j < 4; j++) {
      const int col = n0 + wn * 64 + j * 16 + l15;
      const int h = col >> 6, d = col & 63;
#pragma unroll
      for (int rr = 0; rr < 4; rr++) {
        float val = acc[i][j][rr] + bvv[j];
        const int row = rowb + rr;
        const int b = row >> 11, l = row & 2047;
        if (z == 0) {
          val *= SCALE_LOG2E;
          dst[((size_t)(b * 16 + h) * 2048 + l) * 64 + d] = (__bf16)val;
        } else if (z == 1) {
          dst[((size_t)(b * 16 + h) * 2048 + l) * 64 + d] = (__bf16)val;
        } else {
          dst[((size_t)(b * 16 + h) * 64 + d) * 2048 + l] = (__bf16)val;  // V^T
        }
      }
    }
  }
}

// ---------------------------------------------------------------------------
// Output projection: ctx bf16 [4096][1024] @ Wo^T + bo -> fp32 out
// ---------------------------------------------------------------------------
__global__ __launch_bounds__(256) void gemm_o(const __bf16* __restrict__ ctx, const __bf16* __restrict__ wto,
                                              const float* __restrict__ bo, float* __restrict__ out) {
  __shared__ __align__(16) __bf16 sA[128 * 32];
  __shared__ __align__(16) __bf16 sB[128 * 32];
  const int t = threadIdx.x;
  const int lane = t & 63;
  const int w = t >> 6;
  const int wm = w >> 1, wn = w & 1;
  const int l15 = lane & 15, quad = lane >> 4;
  const int m0 = blockIdx.y * 128, n0 = blockIdx.x * 128;

  floatx4 acc[4][4];
#pragma unroll
  for (int i = 0; i < 4; i++)
#pragma unroll
    for (int j = 0; j < 4; j++) acc[i][j] = (floatx4){0.f, 0.f, 0.f, 0.f};

  gemm_core(ctx, wto, sA, sB, m0, n0, wm, wn, l15, quad, t, acc);

  float bvv[4];
#pragma unroll
  for (int j = 0; j < 4; j++) bvv[j] = bo[n0 + wn * 64 + j * 16 + l15];

#pragma unroll
  for (int i = 0; i < 4; i++) {
    const int rowb = m0 + wm * 64 + i * 16 + quad * 4;
#pragma unroll
    for (int j = 0; j < 4; j++) {
      const int col = n0 + wn * 64 + j * 16 + l15;
#pragma unroll
      for (int rr = 0; rr < 4; rr++)
        out[(size_t)(rowb + rr) * 1024 + col] = acc[i][j][rr] + bvv[j];
    }
  }
}

// ---------------------------------------------------------------------------
// Flash attention, causal. q,k in [bh][L][64]; vT in [bh][64][L] (all bf16).
// Q pre-scaled by 0.125*log2e -> softmax in base 2 (exp2).
// Grid (32, 32); diagonal swizzle qt=(bx+by)&31 balances causal cost per CU.
// No block-shared LDS, no barriers: p_lds is wave-private; K/V read global.
// ---------------------------------------------------------------------------
__global__ __launch_bounds__(256) void flash_attn(const __bf16* __restrict__ q, const __bf16* __restrict__ k,
                                                  const __bf16* __restrict__ vT, __bf16* __restrict__ ctx) {
  __shared__ __align__(16) __bf16 p_lds[4][16 * 72];  // per-wave P tile, stride 72 (16B-aligned rows)

  const int t = threadIdx.x;
  const int lane = t & 63;
  const int w = t >> 6;
  const int l15 = lane & 15, quad = lane >> 4;
  const int bh = blockIdx.y;
  const int qt = (blockIdx.x + blockIdx.y) & 31;
  const int q0 = qt * 64;

  const __bf16* qb = q + (size_t)bh * L * DH;
  const __bf16* kb_ = k + (size_t)bh * L * DH;
  const __bf16* vb = vT + (size_t)bh * DH * L;

  const int qrow = q0 + w * 16 + l15;
  bf16x8 aq0 = *(const bf16x8*)&qb[(size_t)qrow * 64 + quad * 8];
  bf16x8 aq1 = *(const bf16x8*)&qb[(size_t)qrow * 64 + 32 + quad * 8];

  floatx4 o[4];
#pragma unroll
  for (int nt = 0; nt < 4; nt++) o[nt] = (floatx4){0.f, 0.f, 0.f, 0.f};
  float m_i[4] = {NEG_BIG, NEG_BIG, NEG_BIG, NEG_BIG};
  float l_i[4] = {0.f, 0.f, 0.f, 0.f};

  const int qg = q0 + w * 16 + quad * 4;

  for (int it = 0; it <= qt; ++it) {
    const int kt = it * 64;

    // ---- S2 = (Q*scale*log2e) K^T via MFMA; B-frag straight from global K ----
    floatx4 s[4];
#pragma unroll
    for (int jt = 0; jt < 4; jt++) {
      const size_t krow = (size_t)(kt + jt * 16 + l15) * 64;
      bf16x8 bk0 = *(const bf16x8*)&kb_[krow + quad * 8];
      bf16x8 bk1 = *(const bf16x8*)&kb_[krow + 32 + quad * 8];
      floatx4 z = (floatx4){0.f, 0.f, 0.f, 0.f};
      z = MFMA16(aq0, bk0, z);
      z = MFMA16(aq1, bk1, z);
      s[jt] = z;
    }

    // ---- causal mask: only the diagonal tile needs it (uniform branch) ----
    if (it == qt) {
#pragma unroll
      for (int jt = 0; jt < 4; jt++) {
        const int kg = kt + jt * 16 + l15;
#pragma unroll
        for (int rr = 0; rr < 4; rr++)
          if (kg > qg + rr) s[jt][rr] = NEG_BIG;
      }
    }

    // ---- online softmax, base-2 (rows live in one 16-lane quad) ----
#pragma unroll
    for (int rr = 0; rr < 4; rr++) {
      float mx = fmaxf(fmaxf(s[0][rr], s[1][rr]), fmaxf(s[2][rr], s[3][rr]));
      mx = fmaxf(mx, __shfl_xor(mx, 1));
      mx = fmaxf(mx, __shfl_xor(mx, 2));
      mx = fmaxf(mx, __shfl_xor(mx, 4));
      mx = fmaxf(mx, __shfl_xor(mx, 8));
      const float mnew = fmaxf(m_i[rr], mx);
      const float alpha = exp2f(m_i[rr] - mnew);
      float psum = 0.f;
#pragma unroll
      for (int jt = 0; jt < 4; jt++) {
        const float p = exp2f(s[jt][rr] - mnew);
        s[jt][rr] = p;
        psum += p;
      }
      psum += __shfl_xor(psum, 1);
      psum += __shfl_xor(psum, 2);
      psum += __shfl_xor(psum, 4);
      psum += __shfl_xor(psum, 8);
      l_i[rr] = alpha * l_i[rr] + psum;
      m_i[rr] = mnew;
#pragma unroll
      for (int nt = 0; nt < 4; nt++) o[nt][rr] *= alpha;
    }

    // ---- P (C layout) -> wave-private LDS -> A layout (lgkmcnt only) ----
#pragma unroll
    for (int jt = 0; jt < 4; jt++)
#pragma unroll
      for (int rr = 0; rr < 4; rr++)
        p_lds[w][(quad * 4 + rr) * 72 + jt * 16 + l15] = (__bf16)s[jt][rr];

    bf16x8 pf0 = *(const bf16x8*)&p_lds[w][l15 * 72 + quad * 8];
    bf16x8 pf1 = *(const bf16x8*)&p_lds[w][l15 * 72 + 32 + quad * 8];

    // ---- O += P V ; B-frag straight from global V^T (16B coalesced) ----
#pragma unroll
    for (int nt = 0; nt < 4; nt++) {
      const size_t vrow = (size_t)(nt * 16 + l15) * L + kt;
      bf16x8 v0 = *(const bf16x8*)&vb[vrow + quad * 8];
      bf16x8 v1 = *(const bf16x8*)&vb[vrow + 32 + quad * 8];
      o[nt] = MFMA16(pf0, v0, o[nt]);
      o[nt] = MFMA16(pf1, v1, o[nt]);
    }
  }

  // ---- normalize, write ctx [B, L, H*64] ----
  const int b = bh >> 4, h = bh & 15;
#pragma unroll
  for (int rr = 0; rr < 4; rr++) {
    const float inv = 1.f / l_i[rr];
    const int row = q0 + w * 16 + quad * 4 + rr;
#pragma unroll
    for (int nt = 0; nt < 4; nt++) {
      const int col = h * 64 + nt * 16 + l15;
      ctx[((size_t)b * L + row) * 1024 + col] = (__bf16)(o[nt][rr] * inv);
    }
  }
}

// ---------------------------------------------------------------------------
extern "C" void kernel_launch(void* const* d_in, const int* in_sizes, int n_in,
                              void* d_out, int out_size, void* d_ws, size_t ws_size,
                              hipStream_t stream) {
  const float* x_q = (const float*)d_in[0];
  const float* x_k = (const float*)d_in[1];
  const float* x_v = (const float*)d_in[2];
  const float* Wq  = (const float*)d_in[3];
  const float* bq  = (const float*)d_in[4];
  const float* Wk  = (const float*)d_in[5];
  const float* bk  = (const float*)d_in[6];
  const float* Wv  = (const float*)d_in[7];
  const float* bv  = (const float*)d_in[8];
  const float* Wo  = (const float*)d_in[9];
  const float* bo  = (const float*)d_in[10];

  char* ws = (char*)d_ws;
  __bf16* xc  = (__bf16*)ws;                          // 3 x [4096][1024] bf16 (24 MB), dead after gemm_proj
  __bf16* wt  = (__bf16*)(ws + ((size_t)24 << 20));   // 4 x 1024x1024 bf16    (8 MB)
  __bf16* qkv = (__bf16*)(ws + ((size_t)32 << 20));   // q,k [bh][l][d]; vT [bh][d][l] (24 MB)
  __bf16* ctx = (__bf16*)ws;                          // [B,L,1024] (8 MB) — reuses xc region
  __bf16* qp  = qkv;
  __bf16* kp  = qkv + (size_t)BB * L * D;
  __bf16* vtp = qkv + (size_t)2 * BB * L * D;

  cvt_x<<<dim3(1024, 1, 3), 256, 0, stream>>>(x_q, x_k, x_v, xc);
  transpose_w<<<dim3(32, 32, 4), dim3(32, 8), 0, stream>>>(Wq, Wk, Wv, Wo, wt);
  gemm_proj<<<dim3(8, 32, 3), 256, 0, stream>>>(xc, wt, bq, bk, bv, qkv);
  flash_attn<<<dim3(32, 32), 256, 0, stream>>>(qp, kp, vtp, ctx);
  gemm_o<<<dim3(8, 32), 256, 0, stream>>>(ctx, wt + (size_t)3 * D * D, bo, (float*)d_out);
}